// Round 1
// baseline (392.444 us; speedup 1.0000x reference)
//
#include <hip/hip_runtime.h>

// Embedding gather: out[r, :] = weight[indices[r], :]
// indices: 819200 int32, weight: 1,000,000 x 64 fp32 (244 MiB), out: 819200 x 64 fp32.
//
// R4 = R3 with doubled memory-level parallelism:
//  - 8 rows per 16-lane group (was 4): two broadcast i32x4 index loads, then
//    8 INDEPENDENT 16B gathers in flight per thread before any store waits.
//    VGPR cost ~32 extra regs -> still max occupancy; per-SIMD outstanding
//    scattered 256B segments doubles.
//  - non-temporal stores kept: the 210MB output stream must not evict the
//    ~244MiB table from the 256MiB Infinity Cache across replays.

typedef float f32x4 __attribute__((ext_vector_type(4)));
typedef int   i32x4 __attribute__((ext_vector_type(4)));

#define LPR 16  // lanes per row: 64 floats / 4 floats-per-vector
#define RPT 8   // rows per thread (per 16-lane group)

__global__ __launch_bounds__(256) void embed_gather_kernel(
    const int* __restrict__ indices,
    const f32x4* __restrict__ weight,   // row r starts at weight[r*16]
    f32x4* __restrict__ out,
    int num_rows) {
    int tid = blockIdx.x * blockDim.x + threadIdx.x;
    int g = tid >> 4;                 // group id; group handles rows RPT*g .. RPT*g+7
    int lane = tid & (LPR - 1);
    int r0 = g * RPT;
    if (r0 >= num_rows) return;

    if (r0 + RPT - 1 < num_rows) {
        // fast path: two 16B broadcast loads of 8 indices, 8 independent gathers.
        // All 8 gathers issue back-to-back; stores drain them in order.
        i32x4 ia = *(const i32x4*)(indices + r0);
        i32x4 ib = *(const i32x4*)(indices + r0 + 4);
        // 32-bit element offsets: max 1M*16 + 15 < 2^31, saves 64-bit addr VALU
        f32x4 v0 = weight[(unsigned)ia.x * LPR + lane];
        f32x4 v1 = weight[(unsigned)ia.y * LPR + lane];
        f32x4 v2 = weight[(unsigned)ia.z * LPR + lane];
        f32x4 v3 = weight[(unsigned)ia.w * LPR + lane];
        f32x4 v4 = weight[(unsigned)ib.x * LPR + lane];
        f32x4 v5 = weight[(unsigned)ib.y * LPR + lane];
        f32x4 v6 = weight[(unsigned)ib.z * LPR + lane];
        f32x4 v7 = weight[(unsigned)ib.w * LPR + lane];
        unsigned o = (unsigned)r0 * LPR + lane;
        __builtin_nontemporal_store(v0, &out[o]);
        __builtin_nontemporal_store(v1, &out[o + LPR]);
        __builtin_nontemporal_store(v2, &out[o + 2 * LPR]);
        __builtin_nontemporal_store(v3, &out[o + 3 * LPR]);
        __builtin_nontemporal_store(v4, &out[o + 4 * LPR]);
        __builtin_nontemporal_store(v5, &out[o + 5 * LPR]);
        __builtin_nontemporal_store(v6, &out[o + 6 * LPR]);
        __builtin_nontemporal_store(v7, &out[o + 7 * LPR]);
    } else {
        // tail (not hit for 819200 rows, kept for generality)
        for (int r = r0; r < num_rows; ++r) {
            int src = indices[r];
            f32x4 v = weight[(size_t)src * LPR + lane];
            __builtin_nontemporal_store(v, &out[(size_t)r * LPR + lane]);
        }
    }
}

extern "C" void kernel_launch(void* const* d_in, const int* in_sizes, int n_in,
                              void* d_out, int out_size, void* d_ws, size_t ws_size,
                              hipStream_t stream) {
    const int* indices = (const int*)d_in[0];
    const f32x4* weight = (const f32x4*)d_in[1];
    f32x4* out = (f32x4*)d_out;

    int num_rows = in_sizes[0];                        // 819200
    int num_groups = (num_rows + RPT - 1) / RPT;       // 8 rows per 16-lane group
    long long total_threads = (long long)num_groups * LPR;
    int block = 256;
    int grid = (int)((total_threads + block - 1) / block);

    embed_gather_kernel<<<grid, block, 0, stream>>>(indices, weight, out, num_rows);
}